// Round 1
// baseline (500.127 us; speedup 1.0000x reference)
//
#include <hip/hip_runtime.h>
#include <hip/hip_bf16.h>

#define NH 12
#define BWIN 2048

using f32x4  = __attribute__((ext_vector_type(4))) float;
using bf16x8 = __attribute__((ext_vector_type(8))) __bf16;

constexpr float SCALE = 0.17677669529663687f;  // 1/sqrt(32)

// ---------------- K0: weight bf16 conversion + padded bias table ----------------
// biasT layout: [12][64][64] fp32; cols j>=49 = -1e30 (softmax mask), rows i>=49 = 0.
__global__ __launch_bounds__(256) void wa_prep(
    const float* __restrict__ qkv_w, const float* __restrict__ proj_w,
    const float* __restrict__ tbl,
    __bf16* __restrict__ qkv_w_bf, __bf16* __restrict__ proj_w_bf,
    float* __restrict__ biasT) {
  int p = blockIdx.x * 256 + threadIdx.x;
  if (p < 442368) { qkv_w_bf[p] = (__bf16)qkv_w[p]; return; }
  p -= 442368;
  if (p < 147456) { proj_w_bf[p] = (__bf16)proj_w[p]; return; }
  p -= 147456;
  if (p >= 49152) return;
  int h = p >> 12, rem = p & 4095, i = rem >> 6, j = rem & 63;
  float v;
  if (j >= 49) v = -1e30f;
  else if (i >= 49) v = 0.0f;
  else {
    int py = i / 7, px = i % 7, qy = j / 7, qx = j % 7;
    int idx = (py - qy + 6) * 13 + (px - qx + 6);
    v = tbl[idx * NH + h];
  }
  biasT[p] = v;
}

// ---------------- K1: QKV GEMM  qkv = x @ qkv_w^T + qkv_b  (bf16 out) ----------
// M=100352 (=64*1568), N=1152 (=128*9), K=384 (=32*12). Tile 64x128, 4 waves.
__global__ __launch_bounds__(256, 4) void wa_qkv_gemm(
    const float* __restrict__ x, const __bf16* __restrict__ wq,
    const float* __restrict__ qkv_b, __bf16* __restrict__ qkv) {
  const int mb = blockIdx.x, nb = blockIdx.y;
  const int t = threadIdx.x;
  const int lane = t & 63, wv = t >> 6;
  const int lr = lane & 15, ls = lane >> 4;
  __shared__ alignas(16) __bf16 As[64][32];    // swizzled: slot ^ ((row>>1)&3)
  __shared__ alignas(16) __bf16 Bs[128][32];   // row = output col
  __shared__ alignas(16) __bf16 Cs[64][128];
  f32x4 acc[4][2] = {};
  const int arow = t >> 2, aslot = t & 3;
  for (int kk = 0; kk < 12; ++kk) {
    __syncthreads();
    { // stage A (fp32 -> bf16): 64 rows x 32 k
      const float* src = x + (size_t)(mb * 64 + arow) * 384 + kk * 32 + aslot * 8;
      float4 v0 = *(const float4*)src;
      float4 v1 = *(const float4*)(src + 4);
      bf16x8 o;
      o[0] = (__bf16)v0.x; o[1] = (__bf16)v0.y; o[2] = (__bf16)v0.z; o[3] = (__bf16)v0.w;
      o[4] = (__bf16)v1.x; o[5] = (__bf16)v1.y; o[6] = (__bf16)v1.z; o[7] = (__bf16)v1.w;
      *(bf16x8*)(&As[arow][(aslot ^ ((arow >> 1) & 3)) * 8]) = o;
    }
    #pragma unroll
    for (int i = 0; i < 2; ++i) { // stage B: 128 out-cols x 32 k
      int pidx = t + 256 * i;
      int row = pidx >> 2, slot = pidx & 3;
      bf16x8 v = *(const bf16x8*)(wq + (size_t)(nb * 128 + row) * 384 + kk * 32 + slot * 8);
      *(bf16x8*)(&Bs[row][(slot ^ ((row >> 1) & 3)) * 8]) = v;
    }
    __syncthreads();
    bf16x8 af[4], bfr[2];
    #pragma unroll
    for (int rt = 0; rt < 4; ++rt) {
      int row = rt * 16 + lr;
      af[rt] = *(const bf16x8*)(&As[row][(ls ^ ((row >> 1) & 3)) * 8]);
    }
    #pragma unroll
    for (int ct = 0; ct < 2; ++ct) {
      int c = wv * 32 + ct * 16 + lr;
      bfr[ct] = *(const bf16x8*)(&Bs[c][(ls ^ ((c >> 1) & 3)) * 8]);
    }
    #pragma unroll
    for (int rt = 0; rt < 4; ++rt)
      #pragma unroll
      for (int ct = 0; ct < 2; ++ct)
        acc[rt][ct] = __builtin_amdgcn_mfma_f32_16x16x32_bf16(af[rt], bfr[ct], acc[rt][ct], 0, 0, 0);
  }
  __syncthreads();
  #pragma unroll
  for (int ct = 0; ct < 2; ++ct) { // bias + cvt into Cs
    int col = wv * 32 + ct * 16 + lr;
    float b = qkv_b[nb * 128 + col];
    #pragma unroll
    for (int rt = 0; rt < 4; ++rt)
      #pragma unroll
      for (int r = 0; r < 4; ++r)
        Cs[rt * 16 + ls * 4 + r][col] = (__bf16)(acc[rt][ct][r] + b);
  }
  __syncthreads();
  #pragma unroll
  for (int i = 0; i < 4; ++i) { // coalesced 16B stores
    int pidx = t + 256 * i;
    int row = pidx >> 4, sub = pidx & 15;
    *(bf16x8*)(qkv + (size_t)(mb * 64 + row) * 1152 + nb * 128 + sub * 8) =
        *(const bf16x8*)(&Cs[row][sub * 8]);
  }
}

// ---------------- K2: fused per-window attention + proj ----------------
// 1 block = 1 window, 4 waves. Persistent out accumulator [64][384] fp32,
// wave wv owns cols 96*wv..+95. Head loop: stage qkv_h + projW_h, QK^T (one
// MFMA k-step), wave-parallel softmax, P->LDS, V-transpose, PV, h->LDS,
// proj accumulate.
__global__ __launch_bounds__(256, 2) void wa_attn_proj(
    const __bf16* __restrict__ qkv, const __bf16* __restrict__ pw,
    const float* __restrict__ proj_b, const float* __restrict__ biasT,
    float* __restrict__ out) {
  const int w = blockIdx.x;
  const int t = threadIdx.x;
  const int lane = t & 63, wv = t >> 6;
  const int lr = lane & 15, ls = lane >> 4;

  __shared__ alignas(16) __bf16 Qs[64][32];
  __shared__ alignas(16) __bf16 Ks[64][32];
  __shared__ alignas(16) __bf16 Vs[64][32];
  __shared__ alignas(16) __bf16 Vts[32][64];   // V^T, 8-slot swizzle
  __shared__ alignas(16) __bf16 Ps[64][64];    // softmax probs, 8-slot swizzle
  __shared__ alignas(16) __bf16 Hs[64][32];    // attn out per head
  __shared__ alignas(16) __bf16 Wst[384][32];  // projW[:, h*32:+32]

  f32x4 acc[4][6] = {};  // [row-tile][col-tile within wave's 96 cols]

  // zero pad rows 49..63 of Qs,Ks,Vs (persist across heads; stages write rows<49)
  for (int p = t; p < 1440; p += 256) {
    int a = p / 480, rr = p % 480;
    int row = 49 + rr / 32, col = rr % 32;
    (a == 0 ? Qs : a == 1 ? Ks : Vs)[row][col] = (__bf16)0.0f;
  }

  for (int h = 0; h < NH; ++h) {
    __syncthreads();  // prior-iter LDS reads done before restage
    // stage q,k,v head slices: 3 * 49 rows * 4 x 16B
    for (int p = t; p < 588; p += 256) {
      int s = p / 196, rr = p % 196;
      int row = rr >> 2, slot = rr & 3;
      bf16x8 v = *(const bf16x8*)(qkv + (size_t)(w * 49 + row) * 1152 + s * 384 + h * 32 + slot * 8);
      __bf16* dst = (s == 0 ? Qs : s == 1 ? Ks : Vs)[row];
      *(bf16x8*)(dst + (slot ^ ((row >> 1) & 3)) * 8) = v;
    }
    // stage projW slice: 384 rows x 4 x 16B
    for (int p = t; p < 1536; p += 256) {
      int c = p >> 2, slot = p & 3;
      bf16x8 v = *(const bf16x8*)(pw + (size_t)c * 384 + h * 32 + slot * 8);
      *(bf16x8*)(&Wst[c][(slot ^ ((c >> 1) & 3)) * 8]) = v;
    }
    __syncthreads();
    // V transpose Vs -> Vts (LDS->LDS)
    {
      int d = t & 31, n0 = (t >> 5) * 8;
      bf16x8 v;
      #pragma unroll
      for (int e = 0; e < 8; ++e) {
        int n = n0 + e;
        v[e] = Vs[n][((d >> 3) ^ ((n >> 1) & 3)) * 8 + (d & 7)];
      }
      *(bf16x8*)(&Vts[d][(((n0 >> 3) ^ (d & 7)) * 8)]) = v;
    }
    // QK^T: wave wv computes S rows 16*wv..+15 (4 col-tiles, single k-step K=32)
    int qrow = 16 * wv + lr;
    bf16x8 qa = *(const bf16x8*)(&Qs[qrow][(ls ^ ((qrow >> 1) & 3)) * 8]);
    f32x4 zero = {0.f, 0.f, 0.f, 0.f};
    f32x4 sacc[4];
    #pragma unroll
    for (int ct = 0; ct < 4; ++ct) {
      int j = 16 * ct + lr;
      bf16x8 kb = *(const bf16x8*)(&Ks[j][(ls ^ ((j >> 1) & 3)) * 8]);
      sacc[ct] = __builtin_amdgcn_mfma_f32_16x16x32_bf16(qa, kb, zero, 0, 0, 0);
    }
    // softmax (scale + bias + mask via biasT), rows are wave-local
    float vals[4][4];
    #pragma unroll
    for (int ct = 0; ct < 4; ++ct)
      #pragma unroll
      for (int r = 0; r < 4; ++r) {
        int row = 16 * wv + 4 * ls + r;
        int col = 16 * ct + lr;
        vals[ct][r] = fmaf(sacc[ct][r], SCALE, biasT[(h * 64 + row) * 64 + col]);
      }
    #pragma unroll
    for (int r = 0; r < 4; ++r) {
      float m = fmaxf(fmaxf(vals[0][r], vals[1][r]), fmaxf(vals[2][r], vals[3][r]));
      #pragma unroll
      for (int off = 8; off >= 1; off >>= 1) m = fmaxf(m, __shfl_xor(m, off, 16));
      float pr[4], s = 0.f;
      #pragma unroll
      for (int ct = 0; ct < 4; ++ct) { pr[ct] = __expf(vals[ct][r] - m); s += pr[ct]; }
      #pragma unroll
      for (int off = 8; off >= 1; off >>= 1) s += __shfl_xor(s, off, 16);
      float inv = 1.0f / s;
      int row = 16 * wv + 4 * ls + r;
      #pragma unroll
      for (int ct = 0; ct < 4; ++ct) {
        int col = 16 * ct + lr;
        Ps[row][((col >> 3) ^ (row & 7)) * 8 + (col & 7)] = (__bf16)(pr[ct] * inv);
      }
    }
    __syncthreads();  // Ps (all waves) + Vts ready
    // PV: wave wv computes out_h rows 16*wv..+15, d cols 0..31, K=64 (2 steps)
    f32x4 oacc[2] = {zero, zero};
    #pragma unroll
    for (int ks = 0; ks < 2; ++ks) {
      int prow = 16 * wv + lr;
      int kslot = ks * 4 + ls;
      bf16x8 pa = *(const bf16x8*)(&Ps[prow][((kslot ^ (prow & 7)) * 8)]);
      #pragma unroll
      for (int ct = 0; ct < 2; ++ct) {
        int d = 16 * ct + lr;
        bf16x8 vb = *(const bf16x8*)(&Vts[d][((kslot ^ (d & 7)) * 8)]);
        oacc[ct] = __builtin_amdgcn_mfma_f32_16x16x32_bf16(pa, vb, oacc[ct], 0, 0, 0);
      }
    }
    #pragma unroll
    for (int ct = 0; ct < 2; ++ct)
      #pragma unroll
      for (int r = 0; r < 4; ++r) {
        int row = 16 * wv + 4 * ls + r;
        int col = 16 * ct + lr;
        Hs[row][((col >> 3) ^ ((row >> 1) & 3)) * 8 + (col & 7)] = (__bf16)oacc[ct][r];
      }
    __syncthreads();  // Hs ready for all waves
    // proj accumulate: out[:, wave cols] += Hs @ Wst (K=32, 1 step)
    bf16x8 ha[4];
    #pragma unroll
    for (int rt = 0; rt < 4; ++rt) {
      int row = 16 * rt + lr;
      ha[rt] = *(const bf16x8*)(&Hs[row][(ls ^ ((row >> 1) & 3)) * 8]);
    }
    #pragma unroll
    for (int ctt = 0; ctt < 6; ++ctt) {
      int c = 96 * wv + 16 * ctt + lr;
      bf16x8 wb = *(const bf16x8*)(&Wst[c][(ls ^ ((c >> 1) & 3)) * 8]);
      #pragma unroll
      for (int rt = 0; rt < 4; ++rt)
        acc[rt][ctt] = __builtin_amdgcn_mfma_f32_16x16x32_bf16(ha[rt], wb, acc[rt][ctt], 0, 0, 0);
    }
  }
  // epilogue: + proj_b, store rows < 49
  float pb[6];
  #pragma unroll
  for (int ctt = 0; ctt < 6; ++ctt) pb[ctt] = proj_b[96 * wv + 16 * ctt + lr];
  #pragma unroll
  for (int rt = 0; rt < 4; ++rt)
    #pragma unroll
    for (int r = 0; r < 4; ++r) {
      int row = 16 * rt + 4 * ls + r;
      if (row < 49) {
        #pragma unroll
        for (int ctt = 0; ctt < 6; ++ctt) {
          int c = 96 * wv + 16 * ctt + lr;
          out[(size_t)(w * 49 + row) * 384 + c] = acc[rt][ctt][r] + pb[ctt];
        }
      }
    }
}

extern "C" void kernel_launch(void* const* d_in, const int* in_sizes, int n_in,
                              void* d_out, int out_size, void* d_ws, size_t ws_size,
                              hipStream_t stream) {
  const float* x      = (const float*)d_in[0];
  const float* qkv_w  = (const float*)d_in[1];
  const float* qkv_b  = (const float*)d_in[2];
  const float* proj_w = (const float*)d_in[3];
  const float* proj_b = (const float*)d_in[4];
  const float* tbl    = (const float*)d_in[5];
  float* out = (float*)d_out;

  char* ws = (char*)d_ws;
  __bf16* qkv_w_bf  = (__bf16*)ws;                  // 884,736 B
  __bf16* proj_w_bf = (__bf16*)(ws + 884736);       // 294,912 B
  float*  biasT     = (float*)(ws + 1179648);       // 196,608 B
  __bf16* qkv_buf   = (__bf16*)(ws + 1376256);      // 231,211,008 B

  wa_prep<<<2496, 256, 0, stream>>>(qkv_w, proj_w, tbl, qkv_w_bf, proj_w_bf, biasT);
  wa_qkv_gemm<<<dim3(1568, 9), 256, 0, stream>>>(x, qkv_w_bf, qkv_b, qkv_buf);
  wa_attn_proj<<<BWIN, 256, 0, stream>>>(qkv_buf, proj_w_bf, proj_b, biasT, out);
}